// Round 4
// baseline (386.636 us; speedup 1.0000x reference)
//
#include <hip/hip_runtime.h>
#include <hip/hip_fp16.h>

#define N_ATOMS   50000
#define ATOM_FDIM 133
#define HIDDEN    128
#define DEPTH     3
#define N_EDGES   800000
#define N_MOLS    1024
#define BN_EPS    1e-5f
#define K_IN_PAD  160   // 133 padded to 5*32
#define BUCKET    64    // fixed-capacity neighbor bucket (Poisson(16), P(>64) negligible)

typedef _Float16 f16x8 __attribute__((ext_vector_type(8)));
typedef float    f32x4 __attribute__((ext_vector_type(4)));

struct __align__(8) half4pack { __half2 a, b; };

#define LDS_S 40   // padded stride (halves) per 32-half k-chunk row

// ---------------- lite setup: weights->fp16^T, stats zero, mol offsets, wcur zero ----
__global__ void setup_kernel(const float* __restrict__ W_in,
                             const float* __restrict__ W1,
                             const float* __restrict__ W2,
                             const int* __restrict__ seg,
                             __half* __restrict__ Wt,
                             float* __restrict__ stats, int* __restrict__ moloff,
                             int* __restrict__ wcur)
{
    const int NW4 = (128 * K_IN_PAD + 2 * DEPTH * 128 * 128) / 4;   // 29696
    int j = blockIdx.x * 256 + threadIdx.x;
    if (j < NW4) {
        float v[4];
        #pragma unroll
        for (int u = 0; u < 4; ++u) {
            int e = j * 4 + u;
            if (e < 128 * K_IN_PAD) {
                int n = e / K_IN_PAD, k = e - n * K_IN_PAD;
                v[u] = (k < ATOM_FDIM) ? W_in[(size_t)k * 128 + n] : 0.f;
            } else if (e < 128 * K_IN_PAD + DEPTH * 128 * 128) {
                int q = e - 128 * K_IN_PAD;
                int d = q >> 14, r = q & 16383;
                int n = r >> 7, k = r & 127;
                v[u] = W1[((size_t)d * 128 + k) * 128 + n];
            } else {
                int q = e - 128 * K_IN_PAD - DEPTH * 128 * 128;
                int d = q >> 14, r = q & 16383;
                int n = r >> 7, k = r & 127;
                v[u] = W2[((size_t)d * 128 + k) * 128 + n];
            }
        }
        half4pack p;
        p.a = __float22half2_rn(make_float2(v[0], v[1]));
        p.b = __float22half2_rn(make_float2(v[2], v[3]));
        *(half4pack*)&Wt[j * 4] = p;
        return;
    }
    int m = j - NW4;
    if (m < DEPTH * 256) stats[m] = 0.f;
    if (m <= N_MOLS) {
        int lo = 0, hi = N_ATOMS;
        while (lo < hi) {
            int mid = (lo + hi) >> 1;
            if (seg[mid] < m) lo = mid + 1; else hi = mid;
        }
        moloff[m] = lo;
    }
    if (m < N_ATOMS / 4) ((int4*)wcur)[m] = make_int4(0, 0, 0, 0);
}

// ---------------- grid-fused: bucket CSR fill || input-projection MFMA GEMM ----
// Blocks [0, FILLB): one-pass bucket scatter, 1 edge/thread.
//   FILL BLOCKS FIRST: all ~512 resident block slots do atomics initially
//   (round-3 regression: proj-first left only ~121 resident fill blocks ->
//   atomic concurrency starved, 65us -> 85us).
// Blocks [FILLB, FILLB+GB): relu(f_atoms(fp32, inline-cvt) @ W_in^T + b) -> xh.
//   Proj trails and overlaps the fill tail.
#define GB    ((N_ATOMS + 127) / 128)   // 391
#define FILLB ((N_EDGES + 255) / 256)   // 3125

__global__ __launch_bounds__(256, 2) void fill_proj(
    const int* __restrict__ src, const int* __restrict__ tgt,
    int* __restrict__ wcur, unsigned short* __restrict__ col,
    const float* __restrict__ f, const __half* __restrict__ Bt,
    const float* __restrict__ bias, __half* __restrict__ C)
{
    __shared__ __align__(16) __half As[128 * LDS_S];
    __shared__ __align__(16) __half Bs[128 * LDS_S];

    if (blockIdx.x < FILLB) {
        int e = blockIdx.x * 256 + threadIdx.x;
        if (e < N_EDGES) {
            int tg = tgt[e];
            int sv = src[e];
            int p = atomicAdd(&wcur[tg], 1);
            if (p < BUCKET) col[(size_t)tg * BUCKET + p] = (unsigned short)sv;
        }
        return;
    }

    // ---- projection GEMM path (A staged from fp32 with inline conversion) ----
    const int t = threadIdx.x;
    const int w = t >> 6, lane = t & 63;
    const int wm = w >> 1, wn = w & 1;
    const int l15 = lane & 15, quad = lane >> 4;
    const int row0 = (blockIdx.x - FILLB) * 128;
    const int M = N_ATOMS, K = K_IN_PAD;

    f32x4 acc[4][4];
    #pragma unroll
    for (int mt = 0; mt < 4; ++mt)
        #pragma unroll
        for (int nt = 0; nt < 4; ++nt) acc[mt][nt] = (f32x4){0.f, 0.f, 0.f, 0.f};

    for (int k0 = 0; k0 < K; k0 += 32) {
        #pragma unroll
        for (int i = 0; i < 2; ++i) {
            int c = t * 2 + i;
            int r = c >> 2, o = c & 3;
            int row = row0 + r;
            int kb = k0 + o * 8;
            __half h8[8];
            #pragma unroll
            for (int u = 0; u < 8; ++u) {
                int k = kb + u;
                float v = (row < M && k < ATOM_FDIM) ? f[(size_t)row * ATOM_FDIM + k] : 0.f;
                h8[u] = __float2half(v);
            }
            *(uint4*)&As[r * LDS_S + o * 8] = *(uint4*)h8;
        }
        #pragma unroll
        for (int i = 0; i < 2; ++i) {
            int c = t * 2 + i;
            int r = c >> 2, o = c & 3;
            uint4 v = *(const uint4*)&Bt[(size_t)r * K + k0 + o * 8];
            *(uint4*)&Bs[r * LDS_S + o * 8] = v;
        }
        __syncthreads();
        f16x8 af[4], bf[4];
        #pragma unroll
        for (int mt = 0; mt < 4; ++mt)
            af[mt] = *(const f16x8*)&As[(wm * 64 + mt * 16 + l15) * LDS_S + quad * 8];
        #pragma unroll
        for (int nt = 0; nt < 4; ++nt)
            bf[nt] = *(const f16x8*)&Bs[(wn * 64 + nt * 16 + l15) * LDS_S + quad * 8];
        #pragma unroll
        for (int mt = 0; mt < 4; ++mt)
            #pragma unroll
            for (int nt = 0; nt < 4; ++nt)
                acc[mt][nt] = __builtin_amdgcn_mfma_f32_16x16x32_f16(af[mt], bf[nt], acc[mt][nt], 0, 0, 0);
        __syncthreads();
    }

    #pragma unroll
    for (int nt = 0; nt < 4; ++nt) {
        int cc = wn * 64 + nt * 16 + l15;
        float b = bias[cc];
        #pragma unroll
        for (int mt = 0; mt < 4; ++mt) {
            #pragma unroll
            for (int r = 0; r < 4; ++r) {
                int row = row0 + wm * 64 + mt * 16 + quad * 4 + r;
                if (row < M) {
                    float o = fmaxf(acc[mt][nt][r] + b, 0.f);
                    C[(size_t)row * 128 + cc] = __float2half(o);
                }
            }
        }
    }
}

// ---------------- aggregate (wave-per-atom), fused BN+ReLU on source ----------------
// One wave per atom: 50000 waves -> full latency hiding for the random-row gather.
template<bool BN>
__global__ __launch_bounds__(256) void aggregate_kernel(
    const __half2* __restrict__ xh2, const int* __restrict__ cnt,
    const unsigned short* __restrict__ col, const float* __restrict__ eps_param, int d,
    const float* __restrict__ s1, const float* __restrict__ s2,
    const float* __restrict__ gamma, const float* __restrict__ beta, int dprev,
    __half2* __restrict__ aggh2)
{
    int gw = (blockIdx.x * 256 + threadIdx.x) >> 6;   // one wave per atom
    int lane = threadIdx.x & 63;
    float e1 = 1.0f + eps_param[d];

    float2 sc = make_float2(0.f, 0.f), sh = make_float2(0.f, 0.f);
    if (BN) {
        const float inv_n = 1.0f / (float)N_ATOMS;
        int c0 = lane * 2;
        float m0 = s1[c0] * inv_n;
        float v0 = fmaxf(s2[c0] * inv_n - m0 * m0, 0.f);
        float m1 = s1[c0 + 1] * inv_n;
        float v1 = fmaxf(s2[c0 + 1] * inv_n - m1 * m1, 0.f);
        sc.x = gamma[dprev * 128 + c0]     * rsqrtf(v0 + BN_EPS);
        sc.y = gamma[dprev * 128 + c0 + 1] * rsqrtf(v1 + BN_EPS);
        sh.x = beta[dprev * 128 + c0]     - m0 * sc.x;
        sh.y = beta[dprev * 128 + c0 + 1] - m1 * sc.y;
    }

    float2 a = __half22float2(xh2[(size_t)gw * 64 + lane]);
    if (BN) {
        a.x = fmaxf(a.x * sc.x + sh.x, 0.f);
        a.y = fmaxf(a.y * sc.y + sh.y, 0.f);
    }
    float2 acc;
    acc.x = a.x * e1;
    acc.y = a.y * e1;

    int n = min(cnt[gw], BUCKET);
    const unsigned short* bp = &col[(size_t)gw * BUCKET];
    for (int i = 0; i < n; i += 8) {
        #pragma unroll
        for (int u = 0; u < 8; ++u) {
            int idx = i + u;
            int c = bp[min(idx, n - 1)];
            float2 f = __half22float2(xh2[(size_t)c * 64 + lane]);
            if (BN) {
                f.x = fmaxf(f.x * sc.x + sh.x, 0.f);
                f.y = fmaxf(f.y * sc.y + sh.y, 0.f);
            }
            if (idx < n) {
                acc.x += f.x;
                acc.y += f.y;
            }
        }
    }
    aggh2[(size_t)gw * 64 + lane] = __float22half2_rn(acc);
}

// ---------------- FUSED MLP: hpre = relu(agg@W1+b1)@W2+b2, + BN stats ----------------
// GEMM1 A-fragments loaded DIRECT from global (aggh is L2/LLC-resident, just
// written by aggregate): removes the A-stage + one sync from the critical path.
// Rows >= M read garbage but only pollute their own (store/stats-guarded) C rows.
__global__ __launch_bounds__(256, 2) void mlp_fused(
    const __half* __restrict__ A, const __half* __restrict__ B1t,
    const __half* __restrict__ B2t,
    const float* __restrict__ bias1, const float* __restrict__ bias2,
    __half* __restrict__ C, int M,
    float* __restrict__ s1, float* __restrict__ s2)
{
    __shared__ __align__(16) __half As[4 * 128 * LDS_S];  // 40 KB (h buffer)
    __shared__ __align__(16) __half Bs[4 * 128 * LDS_S];  // 40 KB (W1 then W2)

    const int t = threadIdx.x;
    const int w = t >> 6, lane = t & 63;
    const int wm = w >> 1, wn = w & 1;
    const int l15 = lane & 15, quad = lane >> 4;
    const int row0 = blockIdx.x * 128;

    f32x4 acc[4][4];
    #pragma unroll
    for (int mt = 0; mt < 4; ++mt)
        #pragma unroll
        for (int nt = 0; nt < 4; ++nt) acc[mt][nt] = (f32x4){0.f, 0.f, 0.f, 0.f};

    // ---- stage B (W1) only ----
    #pragma unroll
    for (int i = 0; i < 8; ++i) {
        int c = i * 256 + t;
        int r = c >> 4, o = c & 15;
        int kc = o >> 2, oo = o & 3;
        uint4 v = *(const uint4*)&B1t[(size_t)r * 128 + o * 8];
        *(uint4*)&Bs[(kc * 128 + r) * LDS_S + oo * 8] = v;
    }
    __syncthreads();

    // ---- GEMM1: A direct from global ----
    #pragma unroll
    for (int kc = 0; kc < 4; ++kc) {
        f16x8 af[4], bf[4];
        #pragma unroll
        for (int mt = 0; mt < 4; ++mt)
            af[mt] = *(const f16x8*)&A[(size_t)(row0 + wm * 64 + mt * 16 + l15) * 128 + kc * 32 + quad * 8];
        #pragma unroll
        for (int nt = 0; nt < 4; ++nt)
            bf[nt] = *(const f16x8*)&Bs[(kc * 128 + wn * 64 + nt * 16 + l15) * LDS_S + quad * 8];
        #pragma unroll
        for (int mt = 0; mt < 4; ++mt)
            #pragma unroll
            for (int nt = 0; nt < 4; ++nt)
                acc[mt][nt] = __builtin_amdgcn_mfma_f32_16x16x32_f16(af[mt], bf[nt], acc[mt][nt], 0, 0, 0);
    }
    __syncthreads();   // all Bs reads done before overwrite

    // ---- h = relu(acc + b1) -> As (A-layout); restage Bs with W2 ----
    #pragma unroll
    for (int nt = 0; nt < 4; ++nt) {
        int k = wn * 64 + nt * 16 + l15;
        float b = bias1[k];
        int kc = k >> 5, ko = k & 31;
        #pragma unroll
        for (int mt = 0; mt < 4; ++mt) {
            #pragma unroll
            for (int r = 0; r < 4; ++r) {
                int rl = wm * 64 + mt * 16 + quad * 4 + r;
                float h = fmaxf(acc[mt][nt][r] + b, 0.f);
                As[(kc * 128 + rl) * LDS_S + ko] = __float2half(h);
            }
        }
    }
    #pragma unroll
    for (int i = 0; i < 8; ++i) {
        int c = i * 256 + t;
        int r = c >> 4, o = c & 15;
        int kc = o >> 2, oo = o & 3;
        uint4 v = *(const uint4*)&B2t[(size_t)r * 128 + o * 8];
        *(uint4*)&Bs[(kc * 128 + r) * LDS_S + oo * 8] = v;
    }
    __syncthreads();

    // ---- GEMM2 ----
    #pragma unroll
    for (int mt = 0; mt < 4; ++mt)
        #pragma unroll
        for (int nt = 0; nt < 4; ++nt) acc[mt][nt] = (f32x4){0.f, 0.f, 0.f, 0.f};
    #pragma unroll
    for (int kc = 0; kc < 4; ++kc) {
        f16x8 af[4], bf[4];
        #pragma unroll
        for (int mt = 0; mt < 4; ++mt)
            af[mt] = *(const f16x8*)&As[(kc * 128 + wm * 64 + mt * 16 + l15) * LDS_S + quad * 8];
        #pragma unroll
        for (int nt = 0; nt < 4; ++nt)
            bf[nt] = *(const f16x8*)&Bs[(kc * 128 + wn * 64 + nt * 16 + l15) * LDS_S + quad * 8];
        #pragma unroll
        for (int mt = 0; mt < 4; ++mt)
            #pragma unroll
            for (int nt = 0; nt < 4; ++nt)
                acc[mt][nt] = __builtin_amdgcn_mfma_f32_16x16x32_f16(af[mt], bf[nt], acc[mt][nt], 0, 0, 0);
    }

    // ---- epilogue: +b2, BN stats (pre-activation), fp16 store ----
    float ps[4] = {0, 0, 0, 0}, pss[4] = {0, 0, 0, 0};
    #pragma unroll
    for (int nt = 0; nt < 4; ++nt) {
        int cc = wn * 64 + nt * 16 + l15;
        float b = bias2[cc];
        #pragma unroll
        for (int mt = 0; mt < 4; ++mt) {
            #pragma unroll
            for (int r = 0; r < 4; ++r) {
                int row = row0 + wm * 64 + mt * 16 + quad * 4 + r;
                if (row < M) {
                    float o = acc[mt][nt][r] + b;
                    ps[nt] += o;
                    pss[nt] += o * o;
                    C[(size_t)row * 128 + cc] = __float2half(o);
                }
            }
        }
    }

    float* red1 = (float*)As;
    float* red2 = (float*)Bs;
    int contrib = wm * 4 + quad;
    __syncthreads();
    #pragma unroll
    for (int nt = 0; nt < 4; ++nt) {
        int cc = wn * 64 + nt * 16 + l15;
        red1[contrib * 128 + cc] = ps[nt];
        red2[contrib * 128 + cc] = pss[nt];
    }
    __syncthreads();
    if (t < 128) {
        float s = 0.f, q = 0.f;
        #pragma unroll
        for (int g = 0; g < 8; ++g) {
            s += red1[g * 128 + t];
            q += red2[g * 128 + t];
        }
        atomicAdd(&s1[t], s);
        atomicAdd(&s2[t], q);
    }
}

// ---------------- per-molecule mean pooling with fused BN+ReLU ----------------
__global__ void pool_kernel(const __half* __restrict__ hh, const int* __restrict__ off,
                            const float* __restrict__ s1, const float* __restrict__ s2,
                            const float* __restrict__ gamma, const float* __restrict__ beta,
                            int dprev, float* __restrict__ out)
{
    int m = blockIdx.x;
    int c = threadIdx.x;
    const float inv_n = 1.0f / (float)N_ATOMS;
    float mean = s1[c] * inv_n;
    float var = fmaxf(s2[c] * inv_n - mean * mean, 0.f);
    float sc = gamma[dprev * 128 + c] * rsqrtf(var + BN_EPS);
    float sh = beta[dprev * 128 + c] - mean * sc;
    int s = off[m], e = off[m + 1];
    // 4 independent accumulators: break the serial dependent-load chain
    float a0 = 0.f, a1 = 0.f, a2 = 0.f, a3 = 0.f;
    int r = s;
    for (; r + 3 < e; r += 4) {
        float v0 = __half2float(hh[(size_t)(r + 0) * 128 + c]);
        float v1 = __half2float(hh[(size_t)(r + 1) * 128 + c]);
        float v2 = __half2float(hh[(size_t)(r + 2) * 128 + c]);
        float v3 = __half2float(hh[(size_t)(r + 3) * 128 + c]);
        a0 += fmaxf(v0 * sc + sh, 0.f);
        a1 += fmaxf(v1 * sc + sh, 0.f);
        a2 += fmaxf(v2 * sc + sh, 0.f);
        a3 += fmaxf(v3 * sc + sh, 0.f);
    }
    for (; r < e; ++r) {
        float v = __half2float(hh[(size_t)r * 128 + c]);
        a0 += fmaxf(v * sc + sh, 0.f);
    }
    float acc = (a0 + a1) + (a2 + a3);
    int cnt = e - s;
    out[m * 128 + c] = (cnt > 0) ? acc / (float)cnt : 0.f;
}

// ---------------- launcher ----------------
extern "C" void kernel_launch(void* const* d_in, const int* in_sizes, int n_in,
                              void* d_out, int out_size, void* d_ws, size_t ws_size,
                              hipStream_t stream)
{
    const float* f_atoms   = (const float*)d_in[0];
    const float* W_in      = (const float*)d_in[1];
    const float* b_in      = (const float*)d_in[2];
    const float* W1        = (const float*)d_in[3];
    const float* b1        = (const float*)d_in[4];
    const float* W2        = (const float*)d_in[5];
    const float* b2        = (const float*)d_in[6];
    const float* gamma     = (const float*)d_in[7];
    const float* beta      = (const float*)d_in[8];
    const float* eps_param = (const float*)d_in[9];
    const int*   edge_index= (const int*)d_in[10];
    const int*   seg       = (const int*)d_in[11];
    const int*   src = edge_index;
    const int*   tgt = edge_index + N_EDGES;
    float* out = (float*)d_out;

    char* ws = (char*)d_ws;
    size_t off = 0;
    auto alloc = [&](size_t bytes) -> char* {
        char* p = ws + off;
        off += (bytes + 255) & ~(size_t)255;
        return p;
    };
    __half* xh    = (__half*)alloc((size_t)N_ATOMS * HIDDEN * 2);   // x = activations
    __half* aggh  = (__half*)alloc((size_t)N_ATOMS * HIDDEN * 2);   // aggregate out
    __half* hpre  = (__half*)alloc((size_t)N_ATOMS * HIDDEN * 2);   // mlp out (pre-BN h)
    __half* Wt    = (__half*)alloc((size_t)(128 * K_IN_PAD + 2 * DEPTH * 128 * 128) * 2);
    int*   wcur   = (int*)alloc(N_ATOMS * 4);
    unsigned short* col = (unsigned short*)alloc((size_t)N_ATOMS * BUCKET * 2);
    float* s12    = (float*)alloc(DEPTH * 256 * 4);
    int*   moloff = (int*)alloc((N_MOLS + 1) * 4);

    const __half* Wt_in = Wt;
    const __half* W1t   = Wt + 128 * K_IN_PAD;
    const __half* W2t   = W1t + DEPTH * 128 * 128;

    // ---- lite setup: weight conversion + stats/wcur zero + mol offsets ----
    {
        const int NW4 = (128 * K_IN_PAD + 2 * DEPTH * 128 * 128) / 4;   // 29696
        const int TOT = NW4 + N_ATOMS / 4;                              // covers stats/moloff too
        setup_kernel<<<(TOT + 255) / 256, 256, 0, stream>>>(
            W_in, W1, W2, seg, Wt, s12, moloff, wcur);
    }

    // ---- bucket CSR fill (first!) || input projection (grid-fused) ----
    fill_proj<<<FILLB + GB, 256, 0, stream>>>(src, tgt, wcur, col, f_atoms, Wt_in, b_in, xh);

    // ---- layers: wave-per-atom aggregate, then fused MLP ----
    for (int d = 0; d < DEPTH; ++d) {
        float* s1d = s12 + d * 256;
        float* s2d = s1d + 128;
        if (d == 0) {
            aggregate_kernel<false><<<N_ATOMS / 4, 256, 0, stream>>>(
                (const __half2*)xh, wcur, col, eps_param, d,
                nullptr, nullptr, nullptr, nullptr, 0, (__half2*)aggh);
        } else {
            float* s1p = s12 + (d - 1) * 256;
            float* s2p = s1p + 128;
            aggregate_kernel<true><<<N_ATOMS / 4, 256, 0, stream>>>(
                (const __half2*)hpre, wcur, col, eps_param, d,
                s1p, s2p, gamma, beta, d - 1, (__half2*)aggh);
        }
        mlp_fused<<<GB, 256, 0, stream>>>(
            aggh, W1t + (size_t)d * 128 * 128, W2t + (size_t)d * 128 * 128,
            b1 + d * HIDDEN, b2 + d * HIDDEN, hpre, N_ATOMS, s1d, s2d);
    }

    pool_kernel<<<N_MOLS, 128, 0, stream>>>(
        hpre, moloff, s12 + (DEPTH - 1) * 256, s12 + (DEPTH - 1) * 256 + 128,
        gamma, beta, DEPTH - 1, out);
}

// Round 5
// 356.297 us; speedup vs baseline: 1.0852x; 1.0852x over previous
//
#include <hip/hip_runtime.h>
#include <hip/hip_fp16.h>

#define N_ATOMS   50000
#define ATOM_FDIM 133
#define HIDDEN    128
#define DEPTH     3
#define N_EDGES   800000
#define N_MOLS    1024
#define BN_EPS    1e-5f
#define K_IN_PAD  160   // 133 padded to 5*32
#define BUCKET    64    // fixed-capacity neighbor bucket (Poisson(16), P(>64) negligible)

typedef _Float16 f16x8 __attribute__((ext_vector_type(8)));
typedef float    f32x4 __attribute__((ext_vector_type(4)));

struct __align__(8) half4pack { __half2 a, b; };

#define LDS_S 40   // padded stride (halves) per 32-half k-chunk row

// ---------------- lite setup: weights->fp16^T, stats zero, mol offsets, wcur zero ----
__global__ void setup_kernel(const float* __restrict__ W_in,
                             const float* __restrict__ W1,
                             const float* __restrict__ W2,
                             const int* __restrict__ seg,
                             __half* __restrict__ Wt,
                             float* __restrict__ stats, int* __restrict__ moloff,
                             int* __restrict__ wcur)
{
    const int NW4 = (128 * K_IN_PAD + 2 * DEPTH * 128 * 128) / 4;   // 29696
    int j = blockIdx.x * 256 + threadIdx.x;
    if (j < NW4) {
        float v[4];
        #pragma unroll
        for (int u = 0; u < 4; ++u) {
            int e = j * 4 + u;
            if (e < 128 * K_IN_PAD) {
                int n = e / K_IN_PAD, k = e - n * K_IN_PAD;
                v[u] = (k < ATOM_FDIM) ? W_in[(size_t)k * 128 + n] : 0.f;
            } else if (e < 128 * K_IN_PAD + DEPTH * 128 * 128) {
                int q = e - 128 * K_IN_PAD;
                int d = q >> 14, r = q & 16383;
                int n = r >> 7, k = r & 127;
                v[u] = W1[((size_t)d * 128 + k) * 128 + n];
            } else {
                int q = e - 128 * K_IN_PAD - DEPTH * 128 * 128;
                int d = q >> 14, r = q & 16383;
                int n = r >> 7, k = r & 127;
                v[u] = W2[((size_t)d * 128 + k) * 128 + n];
            }
        }
        half4pack p;
        p.a = __float22half2_rn(make_float2(v[0], v[1]));
        p.b = __float22half2_rn(make_float2(v[2], v[3]));
        *(half4pack*)&Wt[j * 4] = p;
        return;
    }
    int m = j - NW4;
    if (m < DEPTH * 256) stats[m] = 0.f;
    if (m <= N_MOLS) {
        int lo = 0, hi = N_ATOMS;
        while (lo < hi) {
            int mid = (lo + hi) >> 1;
            if (seg[mid] < m) lo = mid + 1; else hi = mid;
        }
        moloff[m] = lo;
    }
    if (m < N_ATOMS / 4) ((int4*)wcur)[m] = make_int4(0, 0, 0, 0);
}

// ---------------- grid-fused: bucket CSR fill || input-projection MFMA GEMM ----
// Blocks [0, FILLB): one-pass bucket scatter, 4 edges/thread with int4 loads.
//   R2-verified config (64.9us): 4 independent atomic chains per thread,
//   16B coalesced edge reads, small grid (1173 blocks total) so the trailing
//   proj blocks start early and overlap the fill.
//   (R3: 1/thr proj-first = 80us; R4: 1/thr fill-first = 128us — both worse.)
// Blocks [FILLB, FILLB+GB): relu(f_atoms(fp32, inline-cvt) @ W_in^T + b) -> xh.
#define GB    ((N_ATOMS + 127) / 128)       // 391
#define FILLB ((N_EDGES / 4 + 255) / 256)   // 782

__global__ __launch_bounds__(256, 2) void fill_proj(
    const int* __restrict__ src, const int* __restrict__ tgt,
    int* __restrict__ wcur, unsigned short* __restrict__ col,
    const float* __restrict__ f, const __half* __restrict__ Bt,
    const float* __restrict__ bias, __half* __restrict__ C)
{
    __shared__ __align__(16) __half As[128 * LDS_S];
    __shared__ __align__(16) __half Bs[128 * LDS_S];

    if (blockIdx.x < FILLB) {
        int e4 = (blockIdx.x * 256 + threadIdx.x) * 4;
        if (e4 < N_EDGES) {
            int4 t4 = *(const int4*)&tgt[e4];
            int4 s4 = *(const int4*)&src[e4];
            int p0 = atomicAdd(&wcur[t4.x], 1);
            int p1 = atomicAdd(&wcur[t4.y], 1);
            int p2 = atomicAdd(&wcur[t4.z], 1);
            int p3 = atomicAdd(&wcur[t4.w], 1);
            if (p0 < BUCKET) col[(size_t)t4.x * BUCKET + p0] = (unsigned short)s4.x;
            if (p1 < BUCKET) col[(size_t)t4.y * BUCKET + p1] = (unsigned short)s4.y;
            if (p2 < BUCKET) col[(size_t)t4.z * BUCKET + p2] = (unsigned short)s4.z;
            if (p3 < BUCKET) col[(size_t)t4.w * BUCKET + p3] = (unsigned short)s4.w;
        }
        return;
    }

    // ---- projection GEMM path (A staged from fp32 with inline conversion) ----
    const int t = threadIdx.x;
    const int w = t >> 6, lane = t & 63;
    const int wm = w >> 1, wn = w & 1;
    const int l15 = lane & 15, quad = lane >> 4;
    const int row0 = (blockIdx.x - FILLB) * 128;
    const int M = N_ATOMS, K = K_IN_PAD;

    f32x4 acc[4][4];
    #pragma unroll
    for (int mt = 0; mt < 4; ++mt)
        #pragma unroll
        for (int nt = 0; nt < 4; ++nt) acc[mt][nt] = (f32x4){0.f, 0.f, 0.f, 0.f};

    for (int k0 = 0; k0 < K; k0 += 32) {
        #pragma unroll
        for (int i = 0; i < 2; ++i) {
            int c = t * 2 + i;
            int r = c >> 2, o = c & 3;
            int row = row0 + r;
            int kb = k0 + o * 8;
            __half h8[8];
            #pragma unroll
            for (int u = 0; u < 8; ++u) {
                int k = kb + u;
                float v = (row < M && k < ATOM_FDIM) ? f[(size_t)row * ATOM_FDIM + k] : 0.f;
                h8[u] = __float2half(v);
            }
            *(uint4*)&As[r * LDS_S + o * 8] = *(uint4*)h8;
        }
        #pragma unroll
        for (int i = 0; i < 2; ++i) {
            int c = t * 2 + i;
            int r = c >> 2, o = c & 3;
            uint4 v = *(const uint4*)&Bt[(size_t)r * K + k0 + o * 8];
            *(uint4*)&Bs[r * LDS_S + o * 8] = v;
        }
        __syncthreads();
        f16x8 af[4], bf[4];
        #pragma unroll
        for (int mt = 0; mt < 4; ++mt)
            af[mt] = *(const f16x8*)&As[(wm * 64 + mt * 16 + l15) * LDS_S + quad * 8];
        #pragma unroll
        for (int nt = 0; nt < 4; ++nt)
            bf[nt] = *(const f16x8*)&Bs[(wn * 64 + nt * 16 + l15) * LDS_S + quad * 8];
        #pragma unroll
        for (int mt = 0; mt < 4; ++mt)
            #pragma unroll
            for (int nt = 0; nt < 4; ++nt)
                acc[mt][nt] = __builtin_amdgcn_mfma_f32_16x16x32_f16(af[mt], bf[nt], acc[mt][nt], 0, 0, 0);
        __syncthreads();
    }

    #pragma unroll
    for (int nt = 0; nt < 4; ++nt) {
        int cc = wn * 64 + nt * 16 + l15;
        float b = bias[cc];
        #pragma unroll
        for (int mt = 0; mt < 4; ++mt) {
            #pragma unroll
            for (int r = 0; r < 4; ++r) {
                int row = row0 + wm * 64 + mt * 16 + quad * 4 + r;
                if (row < M) {
                    float o = fmaxf(acc[mt][nt][r] + b, 0.f);
                    C[(size_t)row * 128 + cc] = __float2half(o);
                }
            }
        }
    }
}

// ---------------- aggregate (wave-per-atom), fused BN+ReLU on source ----------------
// One wave per atom: 50000 waves -> full latency hiding for the random-row gather.
template<bool BN>
__global__ __launch_bounds__(256) void aggregate_kernel(
    const __half2* __restrict__ xh2, const int* __restrict__ cnt,
    const unsigned short* __restrict__ col, const float* __restrict__ eps_param, int d,
    const float* __restrict__ s1, const float* __restrict__ s2,
    const float* __restrict__ gamma, const float* __restrict__ beta, int dprev,
    __half2* __restrict__ aggh2)
{
    int gw = (blockIdx.x * 256 + threadIdx.x) >> 6;   // one wave per atom
    int lane = threadIdx.x & 63;
    float e1 = 1.0f + eps_param[d];

    float2 sc = make_float2(0.f, 0.f), sh = make_float2(0.f, 0.f);
    if (BN) {
        const float inv_n = 1.0f / (float)N_ATOMS;
        int c0 = lane * 2;
        float m0 = s1[c0] * inv_n;
        float v0 = fmaxf(s2[c0] * inv_n - m0 * m0, 0.f);
        float m1 = s1[c0 + 1] * inv_n;
        float v1 = fmaxf(s2[c0 + 1] * inv_n - m1 * m1, 0.f);
        sc.x = gamma[dprev * 128 + c0]     * rsqrtf(v0 + BN_EPS);
        sc.y = gamma[dprev * 128 + c0 + 1] * rsqrtf(v1 + BN_EPS);
        sh.x = beta[dprev * 128 + c0]     - m0 * sc.x;
        sh.y = beta[dprev * 128 + c0 + 1] - m1 * sc.y;
    }

    float2 a = __half22float2(xh2[(size_t)gw * 64 + lane]);
    if (BN) {
        a.x = fmaxf(a.x * sc.x + sh.x, 0.f);
        a.y = fmaxf(a.y * sc.y + sh.y, 0.f);
    }
    float2 acc;
    acc.x = a.x * e1;
    acc.y = a.y * e1;

    int n = min(cnt[gw], BUCKET);
    const unsigned short* bp = &col[(size_t)gw * BUCKET];
    for (int i = 0; i < n; i += 8) {
        #pragma unroll
        for (int u = 0; u < 8; ++u) {
            int idx = i + u;
            int c = bp[min(idx, n - 1)];
            float2 f = __half22float2(xh2[(size_t)c * 64 + lane]);
            if (BN) {
                f.x = fmaxf(f.x * sc.x + sh.x, 0.f);
                f.y = fmaxf(f.y * sc.y + sh.y, 0.f);
            }
            if (idx < n) {
                acc.x += f.x;
                acc.y += f.y;
            }
        }
    }
    aggh2[(size_t)gw * 64 + lane] = __float22half2_rn(acc);
}

// ---------------- FUSED MLP: hpre = relu(agg@W1+b1)@W2+b2, + BN stats ----------------
// GEMM1 A-fragments loaded DIRECT from global (aggh is L2/LLC-resident, just
// written by aggregate): removes the A-stage + one sync from the critical path.
__global__ __launch_bounds__(256, 2) void mlp_fused(
    const __half* __restrict__ A, const __half* __restrict__ B1t,
    const __half* __restrict__ B2t,
    const float* __restrict__ bias1, const float* __restrict__ bias2,
    __half* __restrict__ C, int M,
    float* __restrict__ s1, float* __restrict__ s2)
{
    __shared__ __align__(16) __half As[4 * 128 * LDS_S];  // 40 KB (h buffer)
    __shared__ __align__(16) __half Bs[4 * 128 * LDS_S];  // 40 KB (W1 then W2)

    const int t = threadIdx.x;
    const int w = t >> 6, lane = t & 63;
    const int wm = w >> 1, wn = w & 1;
    const int l15 = lane & 15, quad = lane >> 4;
    const int row0 = blockIdx.x * 128;

    f32x4 acc[4][4];
    #pragma unroll
    for (int mt = 0; mt < 4; ++mt)
        #pragma unroll
        for (int nt = 0; nt < 4; ++nt) acc[mt][nt] = (f32x4){0.f, 0.f, 0.f, 0.f};

    // ---- stage B (W1) only ----
    #pragma unroll
    for (int i = 0; i < 8; ++i) {
        int c = i * 256 + t;
        int r = c >> 4, o = c & 15;
        int kc = o >> 2, oo = o & 3;
        uint4 v = *(const uint4*)&B1t[(size_t)r * 128 + o * 8];
        *(uint4*)&Bs[(kc * 128 + r) * LDS_S + oo * 8] = v;
    }
    __syncthreads();

    // ---- GEMM1: A direct from global ----
    #pragma unroll
    for (int kc = 0; kc < 4; ++kc) {
        f16x8 af[4], bf[4];
        #pragma unroll
        for (int mt = 0; mt < 4; ++mt)
            af[mt] = *(const f16x8*)&A[(size_t)(row0 + wm * 64 + mt * 16 + l15) * 128 + kc * 32 + quad * 8];
        #pragma unroll
        for (int nt = 0; nt < 4; ++nt)
            bf[nt] = *(const f16x8*)&Bs[(kc * 128 + wn * 64 + nt * 16 + l15) * LDS_S + quad * 8];
        #pragma unroll
        for (int mt = 0; mt < 4; ++mt)
            #pragma unroll
            for (int nt = 0; nt < 4; ++nt)
                acc[mt][nt] = __builtin_amdgcn_mfma_f32_16x16x32_f16(af[mt], bf[nt], acc[mt][nt], 0, 0, 0);
    }
    __syncthreads();   // all Bs reads done before overwrite

    // ---- h = relu(acc + b1) -> As (A-layout); restage Bs with W2 ----
    #pragma unroll
    for (int nt = 0; nt < 4; ++nt) {
        int k = wn * 64 + nt * 16 + l15;
        float b = bias1[k];
        int kc = k >> 5, ko = k & 31;
        #pragma unroll
        for (int mt = 0; mt < 4; ++mt) {
            #pragma unroll
            for (int r = 0; r < 4; ++r) {
                int rl = wm * 64 + mt * 16 + quad * 4 + r;
                float h = fmaxf(acc[mt][nt][r] + b, 0.f);
                As[(kc * 128 + rl) * LDS_S + ko] = __float2half(h);
            }
        }
    }
    #pragma unroll
    for (int i = 0; i < 8; ++i) {
        int c = i * 256 + t;
        int r = c >> 4, o = c & 15;
        int kc = o >> 2, oo = o & 3;
        uint4 v = *(const uint4*)&B2t[(size_t)r * 128 + o * 8];
        *(uint4*)&Bs[(kc * 128 + r) * LDS_S + oo * 8] = v;
    }
    __syncthreads();

    // ---- GEMM2 ----
    #pragma unroll
    for (int mt = 0; mt < 4; ++mt)
        #pragma unroll
        for (int nt = 0; nt < 4; ++nt) acc[mt][nt] = (f32x4){0.f, 0.f, 0.f, 0.f};
    #pragma unroll
    for (int kc = 0; kc < 4; ++kc) {
        f16x8 af[4], bf[4];
        #pragma unroll
        for (int mt = 0; mt < 4; ++mt)
            af[mt] = *(const f16x8*)&As[(kc * 128 + wm * 64 + mt * 16 + l15) * LDS_S + quad * 8];
        #pragma unroll
        for (int nt = 0; nt < 4; ++nt)
            bf[nt] = *(const f16x8*)&Bs[(kc * 128 + wn * 64 + nt * 16 + l15) * LDS_S + quad * 8];
        #pragma unroll
        for (int mt = 0; mt < 4; ++mt)
            #pragma unroll
            for (int nt = 0; nt < 4; ++nt)
                acc[mt][nt] = __builtin_amdgcn_mfma_f32_16x16x32_f16(af[mt], bf[nt], acc[mt][nt], 0, 0, 0);
    }

    // ---- epilogue: +b2, BN stats (pre-activation), fp16 store ----
    float ps[4] = {0, 0, 0, 0}, pss[4] = {0, 0, 0, 0};
    #pragma unroll
    for (int nt = 0; nt < 4; ++nt) {
        int cc = wn * 64 + nt * 16 + l15;
        float b = bias2[cc];
        #pragma unroll
        for (int mt = 0; mt < 4; ++mt) {
            #pragma unroll
            for (int r = 0; r < 4; ++r) {
                int row = row0 + wm * 64 + mt * 16 + quad * 4 + r;
                if (row < M) {
                    float o = acc[mt][nt][r] + b;
                    ps[nt] += o;
                    pss[nt] += o * o;
                    C[(size_t)row * 128 + cc] = __float2half(o);
                }
            }
        }
    }

    float* red1 = (float*)As;
    float* red2 = (float*)Bs;
    int contrib = wm * 4 + quad;
    __syncthreads();
    #pragma unroll
    for (int nt = 0; nt < 4; ++nt) {
        int cc = wn * 64 + nt * 16 + l15;
        red1[contrib * 128 + cc] = ps[nt];
        red2[contrib * 128 + cc] = pss[nt];
    }
    __syncthreads();
    if (t < 128) {
        float s = 0.f, q = 0.f;
        #pragma unroll
        for (int g = 0; g < 8; ++g) {
            s += red1[g * 128 + t];
            q += red2[g * 128 + t];
        }
        atomicAdd(&s1[t], s);
        atomicAdd(&s2[t], q);
    }
}

// ---------------- per-molecule mean pooling with fused BN+ReLU ----------------
__global__ void pool_kernel(const __half* __restrict__ hh, const int* __restrict__ off,
                            const float* __restrict__ s1, const float* __restrict__ s2,
                            const float* __restrict__ gamma, const float* __restrict__ beta,
                            int dprev, float* __restrict__ out)
{
    int m = blockIdx.x;
    int c = threadIdx.x;
    const float inv_n = 1.0f / (float)N_ATOMS;
    float mean = s1[c] * inv_n;
    float var = fmaxf(s2[c] * inv_n - mean * mean, 0.f);
    float sc = gamma[dprev * 128 + c] * rsqrtf(var + BN_EPS);
    float sh = beta[dprev * 128 + c] - mean * sc;
    int s = off[m], e = off[m + 1];
    float a0 = 0.f, a1 = 0.f, a2 = 0.f, a3 = 0.f;
    int r = s;
    for (; r + 3 < e; r += 4) {
        float v0 = __half2float(hh[(size_t)(r + 0) * 128 + c]);
        float v1 = __half2float(hh[(size_t)(r + 1) * 128 + c]);
        float v2 = __half2float(hh[(size_t)(r + 2) * 128 + c]);
        float v3 = __half2float(hh[(size_t)(r + 3) * 128 + c]);
        a0 += fmaxf(v0 * sc + sh, 0.f);
        a1 += fmaxf(v1 * sc + sh, 0.f);
        a2 += fmaxf(v2 * sc + sh, 0.f);
        a3 += fmaxf(v3 * sc + sh, 0.f);
    }
    for (; r < e; ++r) {
        float v = __half2float(hh[(size_t)r * 128 + c]);
        a0 += fmaxf(v * sc + sh, 0.f);
    }
    float acc = (a0 + a1) + (a2 + a3);
    int cnt = e - s;
    out[m * 128 + c] = (cnt > 0) ? acc / (float)cnt : 0.f;
}

// ---------------- launcher ----------------
extern "C" void kernel_launch(void* const* d_in, const int* in_sizes, int n_in,
                              void* d_out, int out_size, void* d_ws, size_t ws_size,
                              hipStream_t stream)
{
    const float* f_atoms   = (const float*)d_in[0];
    const float* W_in      = (const float*)d_in[1];
    const float* b_in      = (const float*)d_in[2];
    const float* W1        = (const float*)d_in[3];
    const float* b1        = (const float*)d_in[4];
    const float* W2        = (const float*)d_in[5];
    const float* b2        = (const float*)d_in[6];
    const float* gamma     = (const float*)d_in[7];
    const float* beta      = (const float*)d_in[8];
    const float* eps_param = (const float*)d_in[9];
    const int*   edge_index= (const int*)d_in[10];
    const int*   seg       = (const int*)d_in[11];
    const int*   src = edge_index;
    const int*   tgt = edge_index + N_EDGES;
    float* out = (float*)d_out;

    char* ws = (char*)d_ws;
    size_t off = 0;
    auto alloc = [&](size_t bytes) -> char* {
        char* p = ws + off;
        off += (bytes + 255) & ~(size_t)255;
        return p;
    };
    __half* xh    = (__half*)alloc((size_t)N_ATOMS * HIDDEN * 2);   // x = activations
    __half* aggh  = (__half*)alloc((size_t)N_ATOMS * HIDDEN * 2);   // aggregate out
    __half* hpre  = (__half*)alloc((size_t)N_ATOMS * HIDDEN * 2);   // mlp out (pre-BN h)
    __half* Wt    = (__half*)alloc((size_t)(128 * K_IN_PAD + 2 * DEPTH * 128 * 128) * 2);
    int*   wcur   = (int*)alloc(N_ATOMS * 4);
    unsigned short* col = (unsigned short*)alloc((size_t)N_ATOMS * BUCKET * 2);
    float* s12    = (float*)alloc(DEPTH * 256 * 4);
    int*   moloff = (int*)alloc((N_MOLS + 1) * 4);

    const __half* Wt_in = Wt;
    const __half* W1t   = Wt + 128 * K_IN_PAD;
    const __half* W2t   = W1t + DEPTH * 128 * 128;

    // ---- lite setup: weight conversion + stats/wcur zero + mol offsets ----
    {
        const int NW4 = (128 * K_IN_PAD + 2 * DEPTH * 128 * 128) / 4;   // 29696
        const int TOT = NW4 + N_ATOMS / 4;                              // covers stats/moloff too
        setup_kernel<<<(TOT + 255) / 256, 256, 0, stream>>>(
            W_in, W1, W2, seg, Wt, s12, moloff, wcur);
    }

    // ---- bucket CSR fill (4 edges/thr, first) || input projection (grid-fused) ----
    fill_proj<<<FILLB + GB, 256, 0, stream>>>(src, tgt, wcur, col, f_atoms, Wt_in, b_in, xh);

    // ---- layers: wave-per-atom aggregate, then fused MLP ----
    for (int d = 0; d < DEPTH; ++d) {
        float* s1d = s12 + d * 256;
        float* s2d = s1d + 128;
        if (d == 0) {
            aggregate_kernel<false><<<N_ATOMS / 4, 256, 0, stream>>>(
                (const __half2*)xh, wcur, col, eps_param, d,
                nullptr, nullptr, nullptr, nullptr, 0, (__half2*)aggh);
        } else {
            float* s1p = s12 + (d - 1) * 256;
            float* s2p = s1p + 128;
            aggregate_kernel<true><<<N_ATOMS / 4, 256, 0, stream>>>(
                (const __half2*)hpre, wcur, col, eps_param, d,
                s1p, s2p, gamma, beta, d - 1, (__half2*)aggh);
        }
        mlp_fused<<<GB, 256, 0, stream>>>(
            aggh, W1t + (size_t)d * 128 * 128, W2t + (size_t)d * 128 * 128,
            b1 + d * HIDDEN, b2 + d * HIDDEN, hpre, N_ATOMS, s1d, s2d);
    }

    pool_kernel<<<N_MOLS, 128, 0, stream>>>(
        hpre, moloff, s12 + (DEPTH - 1) * 256, s12 + (DEPTH - 1) * 256 + 128,
        gamma, beta, DEPTH - 1, out);
}

// Round 6
// 344.296 us; speedup vs baseline: 1.1230x; 1.0349x over previous
//
#include <hip/hip_runtime.h>
#include <hip/hip_fp16.h>

#define N_ATOMS   50000
#define ATOM_FDIM 133
#define HIDDEN    128
#define DEPTH     3
#define N_EDGES   800000
#define N_MOLS    1024
#define BN_EPS    1e-5f
#define K_IN_PAD  160   // 133 padded to 5*32
#define BUCKET    64    // fixed-capacity neighbor bucket (Poisson(16), P(>64) negligible)

typedef _Float16 f16x8 __attribute__((ext_vector_type(8)));
typedef float    f32x4 __attribute__((ext_vector_type(4)));

struct __align__(8) half4pack { __half2 a, b; };

#define LDS_S 40   // padded stride (halves) per 32-half k-chunk row

// ---------------- heavy setup: atoms->fp16(pad), weights->fp16^T, stats zero,
// ---------------- mol offsets, wcur zero ----------------
// Atom conversion lives HERE (fully parallel, BW-bound) — R5 put it in the
// proj tail (1.5 blocks/CU) and fill_proj went 65 -> 100us.
__global__ void setup_kernel(const float* __restrict__ f,
                             const float* __restrict__ W_in,
                             const float* __restrict__ W1,
                             const float* __restrict__ W2,
                             const int* __restrict__ seg,
                             __half* __restrict__ Ah, __half* __restrict__ Wt,
                             float* __restrict__ stats, int* __restrict__ moloff,
                             int* __restrict__ wcur)
{
    const int NCH = N_ATOMS * (K_IN_PAD / 4);
    const int NW4 = (128 * K_IN_PAD + 2 * DEPTH * 128 * 128) / 4;
    int i = blockIdx.x * 256 + threadIdx.x;
    if (i < NCH) {
        int row = i / (K_IN_PAD / 4);
        int c4  = (i - row * (K_IN_PAD / 4)) * 4;
        float v[4];
        #pragma unroll
        for (int u = 0; u < 4; ++u) {
            int k = c4 + u;
            v[u] = (k < ATOM_FDIM) ? f[(size_t)row * ATOM_FDIM + k] : 0.f;
        }
        half4pack p;
        p.a = __float22half2_rn(make_float2(v[0], v[1]));
        p.b = __float22half2_rn(make_float2(v[2], v[3]));
        *(half4pack*)&Ah[(size_t)row * K_IN_PAD + c4] = p;
        return;
    }
    int j = i - NCH;
    if (j < NW4) {
        float v[4];
        #pragma unroll
        for (int u = 0; u < 4; ++u) {
            int e = j * 4 + u;
            if (e < 128 * K_IN_PAD) {
                int n = e / K_IN_PAD, k = e - n * K_IN_PAD;
                v[u] = (k < ATOM_FDIM) ? W_in[(size_t)k * 128 + n] : 0.f;
            } else if (e < 128 * K_IN_PAD + DEPTH * 128 * 128) {
                int q = e - 128 * K_IN_PAD;
                int d = q >> 14, r = q & 16383;
                int n = r >> 7, k = r & 127;
                v[u] = W1[((size_t)d * 128 + k) * 128 + n];
            } else {
                int q = e - 128 * K_IN_PAD - DEPTH * 128 * 128;
                int d = q >> 14, r = q & 16383;
                int n = r >> 7, k = r & 127;
                v[u] = W2[((size_t)d * 128 + k) * 128 + n];
            }
        }
        half4pack p;
        p.a = __float22half2_rn(make_float2(v[0], v[1]));
        p.b = __float22half2_rn(make_float2(v[2], v[3]));
        *(half4pack*)&Wt[j * 4] = p;
        return;
    }
    int m = j - NW4;
    if (m < DEPTH * 256) stats[m] = 0.f;
    if (m <= N_MOLS) {
        int lo = 0, hi = N_ATOMS;
        while (lo < hi) {
            int mid = (lo + hi) >> 1;
            if (seg[mid] < m) lo = mid + 1; else hi = mid;
        }
        moloff[m] = lo;
    }
    if (m < N_ATOMS / 4) ((int4*)wcur)[m] = make_int4(0, 0, 0, 0);
}

// ---------------- grid-fused: bucket CSR fill || input-projection MFMA GEMM ----
// R2-proven config (64.9us): fill first, 4 edges/thread with int4 loads,
// proj staged from pre-converted fp16 Ah.
#define GB    ((N_ATOMS + 127) / 128)       // 391
#define FILLB ((N_EDGES / 4 + 255) / 256)   // 782

__global__ __launch_bounds__(256, 2) void fill_proj(
    const int* __restrict__ src, const int* __restrict__ tgt,
    int* __restrict__ wcur, unsigned short* __restrict__ col,
    const __half* __restrict__ A, const __half* __restrict__ Bt,
    const float* __restrict__ bias, __half* __restrict__ C)
{
    __shared__ __align__(16) __half As[128 * LDS_S];
    __shared__ __align__(16) __half Bs[128 * LDS_S];

    if (blockIdx.x < FILLB) {
        int e4 = (blockIdx.x * 256 + threadIdx.x) * 4;
        if (e4 < N_EDGES) {
            int4 t4 = *(const int4*)&tgt[e4];
            int4 s4 = *(const int4*)&src[e4];
            int p0 = atomicAdd(&wcur[t4.x], 1);
            int p1 = atomicAdd(&wcur[t4.y], 1);
            int p2 = atomicAdd(&wcur[t4.z], 1);
            int p3 = atomicAdd(&wcur[t4.w], 1);
            if (p0 < BUCKET) col[(size_t)t4.x * BUCKET + p0] = (unsigned short)s4.x;
            if (p1 < BUCKET) col[(size_t)t4.y * BUCKET + p1] = (unsigned short)s4.y;
            if (p2 < BUCKET) col[(size_t)t4.z * BUCKET + p2] = (unsigned short)s4.z;
            if (p3 < BUCKET) col[(size_t)t4.w * BUCKET + p3] = (unsigned short)s4.w;
        }
        return;
    }

    // ---- projection GEMM path (A = fp16 Ah, vectorized staging) ----
    const int t = threadIdx.x;
    const int w = t >> 6, lane = t & 63;
    const int wm = w >> 1, wn = w & 1;
    const int l15 = lane & 15, quad = lane >> 4;
    const int row0 = (blockIdx.x - FILLB) * 128;
    const int M = N_ATOMS, K = K_IN_PAD;

    f32x4 acc[4][4];
    #pragma unroll
    for (int mt = 0; mt < 4; ++mt)
        #pragma unroll
        for (int nt = 0; nt < 4; ++nt) acc[mt][nt] = (f32x4){0.f, 0.f, 0.f, 0.f};

    for (int k0 = 0; k0 < K; k0 += 32) {
        #pragma unroll
        for (int i = 0; i < 2; ++i) {
            int c = t * 2 + i;
            int r = c >> 2, o = c & 3;
            int row = row0 + r;
            uint4 v = make_uint4(0, 0, 0, 0);
            if (row < M) v = *(const uint4*)&A[(size_t)row * K + k0 + o * 8];
            *(uint4*)&As[r * LDS_S + o * 8] = v;
        }
        #pragma unroll
        for (int i = 0; i < 2; ++i) {
            int c = t * 2 + i;
            int r = c >> 2, o = c & 3;
            uint4 v = *(const uint4*)&Bt[(size_t)r * K + k0 + o * 8];
            *(uint4*)&Bs[r * LDS_S + o * 8] = v;
        }
        __syncthreads();
        f16x8 af[4], bf[4];
        #pragma unroll
        for (int mt = 0; mt < 4; ++mt)
            af[mt] = *(const f16x8*)&As[(wm * 64 + mt * 16 + l15) * LDS_S + quad * 8];
        #pragma unroll
        for (int nt = 0; nt < 4; ++nt)
            bf[nt] = *(const f16x8*)&Bs[(wn * 64 + nt * 16 + l15) * LDS_S + quad * 8];
        #pragma unroll
        for (int mt = 0; mt < 4; ++mt)
            #pragma unroll
            for (int nt = 0; nt < 4; ++nt)
                acc[mt][nt] = __builtin_amdgcn_mfma_f32_16x16x32_f16(af[mt], bf[nt], acc[mt][nt], 0, 0, 0);
        __syncthreads();
    }

    #pragma unroll
    for (int nt = 0; nt < 4; ++nt) {
        int cc = wn * 64 + nt * 16 + l15;
        float b = bias[cc];
        #pragma unroll
        for (int mt = 0; mt < 4; ++mt) {
            #pragma unroll
            for (int r = 0; r < 4; ++r) {
                int row = row0 + wm * 64 + mt * 16 + quad * 4 + r;
                if (row < M) {
                    float o = fmaxf(acc[mt][nt][r] + b, 0.f);
                    C[(size_t)row * 128 + cc] = __float2half(o);
                }
            }
        }
    }
}

// ---------------- aggregate (wave-per-atom), shuffle-sourced bucket ----------------
// Lane l loads col[gw*64+l] ONCE (128B coalesced/wave); gather indices come
// from __shfl(colv, idx) — register-sourced, so all n gathers issue without
// the per-batch col-load dependency chain of the previous version.
template<bool BN>
__global__ __launch_bounds__(256) void aggregate_kernel(
    const __half2* __restrict__ xh2, const int* __restrict__ cnt,
    const unsigned short* __restrict__ col, const float* __restrict__ eps_param, int d,
    const float* __restrict__ s1, const float* __restrict__ s2,
    const float* __restrict__ gamma, const float* __restrict__ beta, int dprev,
    __half2* __restrict__ aggh2)
{
    int gw = (blockIdx.x * 256 + threadIdx.x) >> 6;   // one wave per atom
    int lane = threadIdx.x & 63;

    // issue independent loads first: count, whole bucket, self row
    int n = min(cnt[gw], BUCKET);
    int colv = (int)col[(size_t)gw * BUCKET + lane];  // entries >= n are garbage, never shfl'd
    float2 a = __half22float2(xh2[(size_t)gw * 64 + lane]);

    float e1 = 1.0f + eps_param[d];
    float2 sc = make_float2(0.f, 0.f), sh = make_float2(0.f, 0.f);
    if (BN) {
        const float inv_n = 1.0f / (float)N_ATOMS;
        int c0 = lane * 2;
        float m0 = s1[c0] * inv_n;
        float v0 = fmaxf(s2[c0] * inv_n - m0 * m0, 0.f);
        float m1 = s1[c0 + 1] * inv_n;
        float v1 = fmaxf(s2[c0 + 1] * inv_n - m1 * m1, 0.f);
        sc.x = gamma[dprev * 128 + c0]     * rsqrtf(v0 + BN_EPS);
        sc.y = gamma[dprev * 128 + c0 + 1] * rsqrtf(v1 + BN_EPS);
        sh.x = beta[dprev * 128 + c0]     - m0 * sc.x;
        sh.y = beta[dprev * 128 + c0 + 1] - m1 * sc.y;
    }

    if (BN) {
        a.x = fmaxf(a.x * sc.x + sh.x, 0.f);
        a.y = fmaxf(a.y * sc.y + sh.y, 0.f);
    }
    float2 acc;
    acc.x = a.x * e1;
    acc.y = a.y * e1;

    for (int i = 0; i < n; i += 8) {
        #pragma unroll
        for (int u = 0; u < 8; ++u) {
            int idx = i + u;
            int c = __shfl(colv, min(idx, n - 1));   // register-sourced index
            float2 f = __half22float2(xh2[(size_t)c * 64 + lane]);
            if (BN) {
                f.x = fmaxf(f.x * sc.x + sh.x, 0.f);
                f.y = fmaxf(f.y * sc.y + sh.y, 0.f);
            }
            if (idx < n) {
                acc.x += f.x;
                acc.y += f.y;
            }
        }
    }
    aggh2[(size_t)gw * 64 + lane] = __float22half2_rn(acc);
}

// ---------------- FUSED MLP: hpre = relu(agg@W1+b1)@W2+b2, + BN stats ----------------
// GEMM1 A-fragments loaded DIRECT from global (aggh is L2/LLC-resident).
__global__ __launch_bounds__(256, 2) void mlp_fused(
    const __half* __restrict__ A, const __half* __restrict__ B1t,
    const __half* __restrict__ B2t,
    const float* __restrict__ bias1, const float* __restrict__ bias2,
    __half* __restrict__ C, int M,
    float* __restrict__ s1, float* __restrict__ s2)
{
    __shared__ __align__(16) __half As[4 * 128 * LDS_S];  // 40 KB (h buffer)
    __shared__ __align__(16) __half Bs[4 * 128 * LDS_S];  // 40 KB (W1 then W2)

    const int t = threadIdx.x;
    const int w = t >> 6, lane = t & 63;
    const int wm = w >> 1, wn = w & 1;
    const int l15 = lane & 15, quad = lane >> 4;
    const int row0 = blockIdx.x * 128;

    f32x4 acc[4][4];
    #pragma unroll
    for (int mt = 0; mt < 4; ++mt)
        #pragma unroll
        for (int nt = 0; nt < 4; ++nt) acc[mt][nt] = (f32x4){0.f, 0.f, 0.f, 0.f};

    // ---- stage B (W1) only ----
    #pragma unroll
    for (int i = 0; i < 8; ++i) {
        int c = i * 256 + t;
        int r = c >> 4, o = c & 15;
        int kc = o >> 2, oo = o & 3;
        uint4 v = *(const uint4*)&B1t[(size_t)r * 128 + o * 8];
        *(uint4*)&Bs[(kc * 128 + r) * LDS_S + oo * 8] = v;
    }
    __syncthreads();

    // ---- GEMM1: A direct from global ----
    #pragma unroll
    for (int kc = 0; kc < 4; ++kc) {
        f16x8 af[4], bf[4];
        #pragma unroll
        for (int mt = 0; mt < 4; ++mt)
            af[mt] = *(const f16x8*)&A[(size_t)(row0 + wm * 64 + mt * 16 + l15) * 128 + kc * 32 + quad * 8];
        #pragma unroll
        for (int nt = 0; nt < 4; ++nt)
            bf[nt] = *(const f16x8*)&Bs[(kc * 128 + wn * 64 + nt * 16 + l15) * LDS_S + quad * 8];
        #pragma unroll
        for (int mt = 0; mt < 4; ++mt)
            #pragma unroll
            for (int nt = 0; nt < 4; ++nt)
                acc[mt][nt] = __builtin_amdgcn_mfma_f32_16x16x32_f16(af[mt], bf[nt], acc[mt][nt], 0, 0, 0);
    }
    __syncthreads();   // all Bs reads done before overwrite

    // ---- h = relu(acc + b1) -> As (A-layout); restage Bs with W2 ----
    #pragma unroll
    for (int nt = 0; nt < 4; ++nt) {
        int k = wn * 64 + nt * 16 + l15;
        float b = bias1[k];
        int kc = k >> 5, ko = k & 31;
        #pragma unroll
        for (int mt = 0; mt < 4; ++mt) {
            #pragma unroll
            for (int r = 0; r < 4; ++r) {
                int rl = wm * 64 + mt * 16 + quad * 4 + r;
                float h = fmaxf(acc[mt][nt][r] + b, 0.f);
                As[(kc * 128 + rl) * LDS_S + ko] = __float2half(h);
            }
        }
    }
    #pragma unroll
    for (int i = 0; i < 8; ++i) {
        int c = i * 256 + t;
        int r = c >> 4, o = c & 15;
        int kc = o >> 2, oo = o & 3;
        uint4 v = *(const uint4*)&B2t[(size_t)r * 128 + o * 8];
        *(uint4*)&Bs[(kc * 128 + r) * LDS_S + oo * 8] = v;
    }
    __syncthreads();

    // ---- GEMM2 ----
    #pragma unroll
    for (int mt = 0; mt < 4; ++mt)
        #pragma unroll
        for (int nt = 0; nt < 4; ++nt) acc[mt][nt] = (f32x4){0.f, 0.f, 0.f, 0.f};
    #pragma unroll
    for (int kc = 0; kc < 4; ++kc) {
        f16x8 af[4], bf[4];
        #pragma unroll
        for (int mt = 0; mt < 4; ++mt)
            af[mt] = *(const f16x8*)&As[(kc * 128 + wm * 64 + mt * 16 + l15) * LDS_S + quad * 8];
        #pragma unroll
        for (int nt = 0; nt < 4; ++nt)
            bf[nt] = *(const f16x8*)&Bs[(kc * 128 + wn * 64 + nt * 16 + l15) * LDS_S + quad * 8];
        #pragma unroll
        for (int mt = 0; mt < 4; ++mt)
            #pragma unroll
            for (int nt = 0; nt < 4; ++nt)
                acc[mt][nt] = __builtin_amdgcn_mfma_f32_16x16x32_f16(af[mt], bf[nt], acc[mt][nt], 0, 0, 0);
    }

    // ---- epilogue: +b2, BN stats (pre-activation), fp16 store ----
    float ps[4] = {0, 0, 0, 0}, pss[4] = {0, 0, 0, 0};
    #pragma unroll
    for (int nt = 0; nt < 4; ++nt) {
        int cc = wn * 64 + nt * 16 + l15;
        float b = bias2[cc];
        #pragma unroll
        for (int mt = 0; mt < 4; ++mt) {
            #pragma unroll
            for (int r = 0; r < 4; ++r) {
                int row = row0 + wm * 64 + mt * 16 + quad * 4 + r;
                if (row < M) {
                    float o = acc[mt][nt][r] + b;
                    ps[nt] += o;
                    pss[nt] += o * o;
                    C[(size_t)row * 128 + cc] = __float2half(o);
                }
            }
        }
    }

    float* red1 = (float*)As;
    float* red2 = (float*)Bs;
    int contrib = wm * 4 + quad;
    __syncthreads();
    #pragma unroll
    for (int nt = 0; nt < 4; ++nt) {
        int cc = wn * 64 + nt * 16 + l15;
        red1[contrib * 128 + cc] = ps[nt];
        red2[contrib * 128 + cc] = pss[nt];
    }
    __syncthreads();
    if (t < 128) {
        float s = 0.f, q = 0.f;
        #pragma unroll
        for (int g = 0; g < 8; ++g) {
            s += red1[g * 128 + t];
            q += red2[g * 128 + t];
        }
        atomicAdd(&s1[t], s);
        atomicAdd(&s2[t], q);
    }
}

// ---------------- per-molecule mean pooling with fused BN+ReLU ----------------
__global__ void pool_kernel(const __half* __restrict__ hh, const int* __restrict__ off,
                            const float* __restrict__ s1, const float* __restrict__ s2,
                            const float* __restrict__ gamma, const float* __restrict__ beta,
                            int dprev, float* __restrict__ out)
{
    int m = blockIdx.x;
    int c = threadIdx.x;
    const float inv_n = 1.0f / (float)N_ATOMS;
    float mean = s1[c] * inv_n;
    float var = fmaxf(s2[c] * inv_n - mean * mean, 0.f);
    float sc = gamma[dprev * 128 + c] * rsqrtf(var + BN_EPS);
    float sh = beta[dprev * 128 + c] - mean * sc;
    int s = off[m], e = off[m + 1];
    float a0 = 0.f, a1 = 0.f, a2 = 0.f, a3 = 0.f;
    int r = s;
    for (; r + 3 < e; r += 4) {
        float v0 = __half2float(hh[(size_t)(r + 0) * 128 + c]);
        float v1 = __half2float(hh[(size_t)(r + 1) * 128 + c]);
        float v2 = __half2float(hh[(size_t)(r + 2) * 128 + c]);
        float v3 = __half2float(hh[(size_t)(r + 3) * 128 + c]);
        a0 += fmaxf(v0 * sc + sh, 0.f);
        a1 += fmaxf(v1 * sc + sh, 0.f);
        a2 += fmaxf(v2 * sc + sh, 0.f);
        a3 += fmaxf(v3 * sc + sh, 0.f);
    }
    for (; r < e; ++r) {
        float v = __half2float(hh[(size_t)r * 128 + c]);
        a0 += fmaxf(v * sc + sh, 0.f);
    }
    float acc = (a0 + a1) + (a2 + a3);
    int cnt = e - s;
    out[m * 128 + c] = (cnt > 0) ? acc / (float)cnt : 0.f;
}

// ---------------- launcher ----------------
extern "C" void kernel_launch(void* const* d_in, const int* in_sizes, int n_in,
                              void* d_out, int out_size, void* d_ws, size_t ws_size,
                              hipStream_t stream)
{
    const float* f_atoms   = (const float*)d_in[0];
    const float* W_in      = (const float*)d_in[1];
    const float* b_in      = (const float*)d_in[2];
    const float* W1        = (const float*)d_in[3];
    const float* b1        = (const float*)d_in[4];
    const float* W2        = (const float*)d_in[5];
    const float* b2        = (const float*)d_in[6];
    const float* gamma     = (const float*)d_in[7];
    const float* beta      = (const float*)d_in[8];
    const float* eps_param = (const float*)d_in[9];
    const int*   edge_index= (const int*)d_in[10];
    const int*   seg       = (const int*)d_in[11];
    const int*   src = edge_index;
    const int*   tgt = edge_index + N_EDGES;
    float* out = (float*)d_out;

    char* ws = (char*)d_ws;
    size_t off = 0;
    auto alloc = [&](size_t bytes) -> char* {
        char* p = ws + off;
        off += (bytes + 255) & ~(size_t)255;
        return p;
    };
    __half* xh    = (__half*)alloc((size_t)N_ATOMS * HIDDEN * 2);   // x = activations
    __half* aggh  = (__half*)alloc((size_t)N_ATOMS * HIDDEN * 2);   // aggregate out
    __half* hpre  = (__half*)alloc((size_t)N_ATOMS * HIDDEN * 2);   // mlp out (pre-BN h)
    __half* Ah    = (__half*)alloc((size_t)N_ATOMS * K_IN_PAD * 2);
    __half* Wt    = (__half*)alloc((size_t)(128 * K_IN_PAD + 2 * DEPTH * 128 * 128) * 2);
    int*   wcur   = (int*)alloc(N_ATOMS * 4);
    unsigned short* col = (unsigned short*)alloc((size_t)N_ATOMS * BUCKET * 2);
    float* s12    = (float*)alloc(DEPTH * 256 * 4);
    int*   moloff = (int*)alloc((N_MOLS + 1) * 4);

    const __half* Wt_in = Wt;
    const __half* W1t   = Wt + 128 * K_IN_PAD;
    const __half* W2t   = W1t + DEPTH * 128 * 128;

    // ---- heavy setup: atom+weight fp16 conversion + stats/wcur zero + mol offsets ----
    {
        const int NCH = N_ATOMS * (K_IN_PAD / 4);
        const int NW4 = (128 * K_IN_PAD + 2 * DEPTH * 128 * 128) / 4;
        const int TOT = NCH + NW4 + N_ATOMS / 4;
        setup_kernel<<<(TOT + 255) / 256, 256, 0, stream>>>(
            f_atoms, W_in, W1, W2, seg, Ah, Wt, s12, moloff, wcur);
    }

    // ---- bucket CSR fill (4 edges/thr, first) || input projection (grid-fused) ----
    fill_proj<<<FILLB + GB, 256, 0, stream>>>(src, tgt, wcur, col, Ah, Wt_in, b_in, xh);

    // ---- layers: wave-per-atom aggregate (shuffle bucket), then fused MLP ----
    for (int d = 0; d < DEPTH; ++d) {
        float* s1d = s12 + d * 256;
        float* s2d = s1d + 128;
        if (d == 0) {
            aggregate_kernel<false><<<N_ATOMS / 4, 256, 0, stream>>>(
                (const __half2*)xh, wcur, col, eps_param, d,
                nullptr, nullptr, nullptr, nullptr, 0, (__half2*)aggh);
        } else {
            float* s1p = s12 + (d - 1) * 256;
            float* s2p = s1p + 128;
            aggregate_kernel<true><<<N_ATOMS / 4, 256, 0, stream>>>(
                (const __half2*)hpre, wcur, col, eps_param, d,
                s1p, s2p, gamma, beta, d - 1, (__half2*)aggh);
        }
        mlp_fused<<<GB, 256, 0, stream>>>(
            aggh, W1t + (size_t)d * 128 * 128, W2t + (size_t)d * 128 * 128,
            b1 + d * HIDDEN, b2 + d * HIDDEN, hpre, N_ATOMS, s1d, s2d);
    }

    pool_kernel<<<N_MOLS, 128, 0, stream>>>(
        hpre, moloff, s12 + (DEPTH - 1) * 256, s12 + (DEPTH - 1) * 256 + 128,
        gamma, beta, DEPTH - 1, out);
}